// Round 4
// baseline (388.893 us; speedup 1.0000x reference)
//
#include <hip/hip_runtime.h>
#include <hip/hip_bf16.h>

#define HID   768
#define DW    384                 // dwords per row (bf16x2)
#define BATCH 8192
#define TPB   256
#define SPB   8                   // samples per block (4 waves x 2)
#define NBLK  (BATCH / SPB)       // 1024
#define PI_F  3.14159265358979323846f

typedef unsigned int uint;

__device__ __forceinline__ float bflo(uint u) { return __uint_as_float(u << 16); }
__device__ __forceinline__ float bfhi(uint u) { return __uint_as_float(u & 0xffff0000u); }
__device__ __forceinline__ uint  f2bf(float x) {
    uint u = __float_as_uint(x);
    return (u + 0x7fffu + ((u >> 16) & 1u)) >> 16;     // RNE
}
__device__ __forceinline__ float tanh_fast(float z) {
    float e = __expf(z + z);
    return fmaf(-2.f, __builtin_amdgcn_rcpf(e + 1.f), 1.f);
}

// fallback circuit (fp32 path; math verified rounds 1-3)
__device__ void circuit_qc(const float* zz, const float* qc, float* meas) {
    float sc[8], cc[8];
    #pragma unroll
    for (int j = 0; j < 8; ++j) {
        float t_ = tanhf(zz[j]);
        sc[j] = sinpif(t_);
        cc[j] = cospif(t_);
    }
    float PA = 1.f, PB = 1.f, Fr = 1.f, Fi = 0.f;
    #pragma unroll
    for (int j = 1; j < 8; ++j) {
        float DA = qc[4*j], DB = qc[4*j+1], Kr = qc[4*j+2], Ki = qc[4*j+3];
        float ca = 0.5f*(DA+DB), da = 0.5f*(DA-DB);
        float u = da * cc[j];
        float v = fmaf(Kr, sc[j], ca);
        meas[j] = fmaf(cc[0], u, v);
        PA *= (v + u); PB *= (v - u);
        float fi = cc[j]*Ki;
        float nr = Fr*Kr - Fi*fi;
        Fi = Fr*fi + Fi*Kr; Fr = nr;
    }
    meas[0] = 0.5f*(1.f+cc[0])*qc[0]*PA + 0.5f*(1.f-cc[0])*qc[1]*PB
            + sc[0]*(qc[2]*Fr - qc[3]*Fi);
}

__global__ __launch_bounds__(TPB, 2) void fused_kernel(
    const void* H_, const void* WI_, const void* bin_, const void* WO_,
    const void* bout_, const void* wry_, const void* wrz_,
    const void* gam_, const void* bet_, void* out_)
{
    __shared__ uint sWin[8][DW];    // W_in rows verbatim: plane j, dword cp = cols (2cp,2cp+1)
    __shared__ uint sWout[8][DW];   // plane j, dword cp = (W_out[2cp][j], W_out[2cp+1][j])
    __shared__ uint sBout[DW], sGam[DW], sBet[DW];

    const int tid = threadIdx.x;
    const uint* Hd = (const uint*)H_;

    // ---- dtype sniff: block-uniform via syncthreads_count ----
    uint probe = Hd[(size_t)blockIdx.x * (SPB * DW) + tid];
    uint l0 = probe & 0xffffu, h0 = probe >> 16;
    uint e0 = (l0 >> 7) & 0xffu, e1 = (h0 >> 7) & 0xffu;
    bool okk = (l0 == 0u || (e0 >= 100u && e0 <= 133u)) &&
               (h0 == 0u || (e1 >= 100u && e1 <= 133u));
    int nok = __syncthreads_count(okk ? 1 : 0);

    if (nok >= TPB / 2) {
        // ================= bf16 fast path =================
        const uint* WId = (const uint*)WI_;
        const uint* WOd = (const uint*)WO_;
        const uint* BOd = (const uint*)bout_;
        const uint* GAd = (const uint*)gam_;
        const uint* BEd = (const uint*)bet_;
        const __hip_bfloat16* WRY = (const __hip_bfloat16*)wry_;
        const __hip_bfloat16* WRZ = (const __hip_bfloat16*)wrz_;
        uint* Od = (uint*)out_;

        // ---- stage weights to LDS ----
        #pragma unroll
        for (int i = 0; i < 12; ++i)
            ((uint*)sWin)[tid + i*TPB] = WId[tid + i*TPB];
        for (int cp = tid; cp < DW; cp += TPB) {
            uint4 a = *(const uint4*)(WOd + (size_t)cp*8);      // row 2cp
            uint4 b = *(const uint4*)(WOd + (size_t)cp*8 + 4);  // row 2cp+1
            sWout[0][cp] = (a.x & 0xffffu) | (b.x << 16);
            sWout[1][cp] = (a.x >> 16)     | (b.x & 0xffff0000u);
            sWout[2][cp] = (a.y & 0xffffu) | (b.y << 16);
            sWout[3][cp] = (a.y >> 16)     | (b.y & 0xffff0000u);
            sWout[4][cp] = (a.z & 0xffffu) | (b.z << 16);
            sWout[5][cp] = (a.z >> 16)     | (b.z & 0xffff0000u);
            sWout[6][cp] = (a.w & 0xffffu) | (b.w << 16);
            sWout[7][cp] = (a.w >> 16)     | (b.w & 0xffff0000u);
            sBout[cp] = BOd[cp]; sGam[cp] = GAd[cp]; sBet[cp] = BEd[cp];
        }

        // ---- per-lane qubit constants (lane&7 owns its qubit) ----
        float ca_, da_, kr_, ki_;
        {
            int q = tid & 7;
            float ry0 = __bfloat162float(WRY[q]);
            float ry1 = __bfloat162float(WRY[8 + q]);
            float rz0 = __bfloat162float(WRZ[q]);
            float rz1 = __bfloat162float(WRZ[8 + q]);
            float cA = cosf(0.5f*ry0), sA = sinf(0.5f*ry0);
            float cB = cosf(0.5f*ry1), sB = sinf(0.5f*ry1);
            float p0c = cosf(0.5f*rz0), p0s = sinf(0.5f*rz0);
            float p1c = cosf(0.5f*rz1), p1s = sinf(0.5f*rz1);
            float g00r =  cA*p0c, g00i = -cA*p0s;
            float g01r = -sA*p0c, g01i =  sA*p0s;
            float g10r =  sA*p0c, g10i =  sA*p0s;
            float g11r =  cA*p0c, g11i =  cA*p0s;
            float h00r = cB*g00r - sB*g10r, h00i = cB*g00i - sB*g10i;
            float h01r = cB*g01r - sB*g11r, h01i = cB*g01i - sB*g11i;
            float h10r = sB*g00r + cB*g10r, h10i = sB*g00i + cB*g10i;
            float h11r = sB*g01r + cB*g11r, h11i = sB*g01i + cB*g11i;
            float f00r = h00r*p1c + h00i*p1s, f00i = h00i*p1c - h00r*p1s;
            float f01r = h01r*p1c + h01i*p1s, f01i = h01i*p1c - h01r*p1s;
            float f10r = h10r*p1c - h10i*p1s, f10i = h10i*p1c + h10r*p1s;
            float f11r = h11r*p1c - h11i*p1s, f11i = h11i*p1c + h11r*p1s;
            float DA = f00r*f00r + f00i*f00i - (f10r*f10r + f10i*f10i);
            float DB = f01r*f01r + f01i*f01i - (f11r*f11r + f11i*f11i);
            float Kr = (f00r*f01r + f00i*f01i) - (f10r*f11r + f10i*f11i);
            float Ki = (f00i*f01r - f00r*f01i) - (f10i*f11r - f10r*f11i);
            ca_ = 0.5f*(DA + DB); da_ = 0.5f*(DA - DB); kr_ = Kr; ki_ = Ki;
        }
        float bin0[8];
        {
            uint4 bi = *(const uint4*)bin_;
            bin0[0]=bflo(bi.x); bin0[1]=bfhi(bi.x); bin0[2]=bflo(bi.y); bin0[3]=bfhi(bi.y);
            bin0[4]=bflo(bi.z); bin0[5]=bfhi(bi.z); bin0[6]=bflo(bi.w); bin0[7]=bfhi(bi.w);
        }
        __syncthreads();

        const int lane = tid & 63;
        const int wv   = tid >> 6;
        const size_t r0 = (size_t)blockIdx.x * SPB + wv * 2;
        const uint* hA = Hd + r0 * DW;
        const uint* hB = hA + DW;

        // ---- phase A: z = hidden @ W_in^T (2 samples/wave) ----
        uint hAv[6], hBv[6];
        #pragma unroll
        for (int t = 0; t < 6; ++t) { hAv[t] = hA[t*64 + lane]; hBv[t] = hB[t*64 + lane]; }
        float zA[8] = {0,0,0,0,0,0,0,0}, zB[8] = {0,0,0,0,0,0,0,0};
        #pragma unroll
        for (int t = 0; t < 6; ++t) {
            int cp = t*64 + lane;
            float a0 = bflo(hAv[t]), a1 = bfhi(hAv[t]);
            float b0 = bflo(hBv[t]), b1 = bfhi(hBv[t]);
            #pragma unroll
            for (int j = 0; j < 8; ++j) {
                uint wj = sWin[j][cp];
                float w0 = bflo(wj), w1 = bfhi(wj);
                zA[j] = fmaf(a0, w0, zA[j]); zA[j] = fmaf(a1, w1, zA[j]);
                zB[j] = fmaf(b0, w0, zB[j]); zB[j] = fmaf(b1, w1, zB[j]);
            }
        }
        #pragma unroll
        for (int d = 1; d < 64; d <<= 1) {
            #pragma unroll
            for (int j = 0; j < 8; ++j) {
                zA[j] += __shfl_xor(zA[j], d, 64);
                zB[j] += __shfl_xor(zB[j], d, 64);
            }
        }

        // ---- circuit (both samples; wave-uniform result) ----
        float mA[8], mB[8];
        {
            float sc0[8], cc0[8], sc1[8], cc1[8];
            #pragma unroll
            for (int j = 0; j < 8; ++j) {
                float t0 = tanh_fast(zA[j] + bin0[j]);
                sc0[j] = __sinf(PI_F * t0); cc0[j] = __cosf(PI_F * t0);
                float t1 = tanh_fast(zB[j] + bin0[j]);
                sc1[j] = __sinf(PI_F * t1); cc1[j] = __cosf(PI_F * t1);
            }
            float PA0=1.f, PB0=1.f, F0r=1.f, F0i=0.f;
            float PA1=1.f, PB1=1.f, F1r=1.f, F1i=0.f;
            #pragma unroll
            for (int j = 1; j < 8; ++j) {
                float caj = __shfl(ca_, j, 64), daj = __shfl(da_, j, 64);
                float krj = __shfl(kr_, j, 64), kij = __shfl(ki_, j, 64);
                { float u = daj*cc0[j], v = fmaf(krj, sc0[j], caj);
                  mA[j] = fmaf(cc0[0], u, v);
                  PA0 *= (v+u); PB0 *= (v-u);
                  float fi = cc0[j]*kij;
                  float nr = F0r*krj - F0i*fi; F0i = F0r*fi + F0i*krj; F0r = nr; }
                { float u = daj*cc1[j], v = fmaf(krj, sc1[j], caj);
                  mB[j] = fmaf(cc1[0], u, v);
                  PA1 *= (v+u); PB1 *= (v-u);
                  float fi = cc1[j]*kij;
                  float nr = F1r*krj - F1i*fi; F1i = F1r*fi + F1i*krj; F1r = nr; }
            }
            float ca0 = __shfl(ca_, 0, 64), da0 = __shfl(da_, 0, 64);
            float kr0 = __shfl(kr_, 0, 64), ki0 = __shfl(ki_, 0, 64);
            float DA0 = ca0 + da0, DB0 = ca0 - da0;
            mA[0] = 0.5f*(1.f+cc0[0])*DA0*PA0 + 0.5f*(1.f-cc0[0])*DB0*PB0
                  + sc0[0]*(kr0*F0r - ki0*F0i);
            mB[0] = 0.5f*(1.f+cc1[0])*DA0*PA1 + 0.5f*(1.f-cc1[0])*DB0*PB1
                  + sc1[0]*(kr0*F1r - ki0*F1i);
        }

        // ---- phase C: y = meas @ W_out^T + b_out; LN; store ----
        float y0A[6], y1A[6], y0B[6], y1B[6];
        float s1A=0.f, s2A=0.f, s1B=0.f, s2B=0.f;
        #pragma unroll
        for (int t = 0; t < 6; ++t) {
            int cp = t*64 + lane;
            uint bo = sBout[cp];
            float v0A = bflo(bo), v1A = bfhi(bo);
            float v0B = v0A, v1B = v1A;
            #pragma unroll
            for (int j = 0; j < 8; ++j) {
                uint wj = sWout[j][cp];
                float w0 = bflo(wj), w1 = bfhi(wj);
                v0A = fmaf(mA[j], w0, v0A); v1A = fmaf(mA[j], w1, v1A);
                v0B = fmaf(mB[j], w0, v0B); v1B = fmaf(mB[j], w1, v1B);
            }
            y0A[t]=v0A; y1A[t]=v1A; y0B[t]=v0B; y1B[t]=v1B;
            s1A += v0A + v1A; s2A = fmaf(v0A,v0A,s2A); s2A = fmaf(v1A,v1A,s2A);
            s1B += v0B + v1B; s2B = fmaf(v0B,v0B,s2B); s2B = fmaf(v1B,v1B,s2B);
        }
        #pragma unroll
        for (int d = 1; d < 64; d <<= 1) {
            s1A += __shfl_xor(s1A, d, 64); s2A += __shfl_xor(s2A, d, 64);
            s1B += __shfl_xor(s1B, d, 64); s2B += __shfl_xor(s2B, d, 64);
        }
        float muA = s1A*(1.f/HID), rsA = rsqrtf(s2A*(1.f/HID) - muA*muA + 1e-5f);
        float muB = s1B*(1.f/HID), rsB = rsqrtf(s2B*(1.f/HID) - muB*muB + 1e-5f);
        uint* oA = Od + r0 * DW;
        uint* oB = oA + DW;
        #pragma unroll
        for (int t = 0; t < 6; ++t) {
            int cp = t*64 + lane;
            uint g = sGam[cp], be = sBet[cp];
            float g0 = bflo(g), g1 = bfhi(g), e0_ = bflo(be), e1_ = bfhi(be);
            float a0 = (y0A[t]-muA)*rsA*g0 + e0_;
            float a1 = (y1A[t]-muA)*rsA*g1 + e1_;
            oA[cp] = f2bf(a0) | (f2bf(a1) << 16);
            float b0 = (y0B[t]-muB)*rsB*g0 + e0_;
            float b1 = (y1B[t]-muB)*rsB*g1 + e1_;
            oB[cp] = f2bf(b0) | (f2bf(b1) << 16);
        }
    } else {
        // ================= fp32 fallback (correctness only) =================
        int s = blockIdx.x * TPB + tid;
        if (s >= BATCH) return;
        const float* H  = (const float*)H_;
        const float* WI = (const float*)WI_;
        const float* WO = (const float*)WO_;
        const float* BI = (const float*)bin_;
        const float* BO = (const float*)bout_;
        const float* WRY = (const float*)wry_;
        const float* WRZ = (const float*)wrz_;
        const float* GA = (const float*)gam_;
        const float* BE = (const float*)bet_;
        float* O = (float*)out_;
        float qc[32];
        for (int q = 0; q < 8; ++q) {
            float ry0 = WRY[q], ry1 = WRY[8+q], rz0 = WRZ[q], rz1 = WRZ[8+q];
            float cA = cosf(0.5f*ry0), sA = sinf(0.5f*ry0);
            float cB = cosf(0.5f*ry1), sB = sinf(0.5f*ry1);
            float p0c = cosf(0.5f*rz0), p0s = sinf(0.5f*rz0);
            float p1c = cosf(0.5f*rz1), p1s = sinf(0.5f*rz1);
            float g00r =  cA*p0c, g00i = -cA*p0s;
            float g01r = -sA*p0c, g01i =  sA*p0s;
            float g10r =  sA*p0c, g10i =  sA*p0s;
            float g11r =  cA*p0c, g11i =  cA*p0s;
            float h00r = cB*g00r - sB*g10r, h00i = cB*g00i - sB*g10i;
            float h01r = cB*g01r - sB*g11r, h01i = cB*g01i - sB*g11i;
            float h10r = sB*g00r + cB*g10r, h10i = sB*g00i + cB*g10i;
            float h11r = sB*g01r + cB*g11r, h11i = sB*g01i + cB*g11i;
            float f00r = h00r*p1c + h00i*p1s, f00i = h00i*p1c - h00r*p1s;
            float f01r = h01r*p1c + h01i*p1s, f01i = h01i*p1c - h01r*p1s;
            float f10r = h10r*p1c - h10i*p1s, f10i = h10i*p1c + h10r*p1s;
            float f11r = h11r*p1c - h11i*p1s, f11i = h11i*p1c + h11r*p1s;
            qc[q*4+0] = f00r*f00r + f00i*f00i - (f10r*f10r + f10i*f10i);
            qc[q*4+1] = f01r*f01r + f01i*f01i - (f11r*f11r + f11i*f11i);
            qc[q*4+2] = (f00r*f01r + f00i*f01i) - (f10r*f11r + f10i*f11i);
            qc[q*4+3] = (f00i*f01r - f00r*f01i) - (f10i*f11r - f10r*f11i);
        }
        float z[8];
        #pragma unroll
        for (int j = 0; j < 8; ++j) z[j] = BI[j];
        for (int c = 0; c < HID; ++c) {
            float h = H[(size_t)s*HID + c];
            #pragma unroll
            for (int j = 0; j < 8; ++j) z[j] = fmaf(h, WI[j*HID + c], z[j]);
        }
        float meas[8];
        circuit_qc(z, qc, meas);
        float s1 = 0.f, s2 = 0.f;
        for (int h = 0; h < HID; ++h) {
            float v = BO[h];
            #pragma unroll
            for (int j = 0; j < 8; ++j) v = fmaf(meas[j], WO[h*8 + j], v);
            s1 += v; s2 = fmaf(v, v, s2);
        }
        float mu = s1*(1.f/HID);
        float rs = rsqrtf(s2*(1.f/HID) - mu*mu + 1e-5f);
        for (int h = 0; h < HID; ++h) {
            float v = BO[h];
            #pragma unroll
            for (int j = 0; j < 8; ++j) v = fmaf(meas[j], WO[h*8 + j], v);
            O[(size_t)s*HID + h] = (v - mu)*rs*GA[h] + BE[h];
        }
    }
}

extern "C" void kernel_launch(void* const* d_in, const int* in_sizes, int n_in,
                              void* d_out, int out_size, void* d_ws, size_t ws_size,
                              hipStream_t stream) {
    fused_kernel<<<NBLK, TPB, 0, stream>>>(
        d_in[0], d_in[1], d_in[2], d_in[3], d_in[4],
        d_in[5], d_in[6], d_in[7], d_in[8], d_out);
}

// Round 5
// 381.326 us; speedup vs baseline: 1.0198x; 1.0198x over previous
//
#include <hip/hip_runtime.h>
#include <hip/hip_bf16.h>

#define HID   768
#define DW    384                 // dwords per row (bf16x2)
#define BATCH 8192
#define TPB   256
#define SPB   8                   // samples per block (4 waves x 2)
#define NBLK  (BATCH / SPB)       // 1024
#define PI_F  3.14159265358979323846f

typedef unsigned int uint;

__device__ __forceinline__ float bflo(uint u) { return __uint_as_float(u << 16); }
__device__ __forceinline__ float bfhi(uint u) { return __uint_as_float(u & 0xffff0000u); }
__device__ __forceinline__ uint  f2bf(float x) {
    uint u = __float_as_uint(x);
    return (u + 0x7fffu + ((u >> 16) & 1u)) >> 16;     // RNE
}
__device__ __forceinline__ float tanh_fast(float z) {
    float e = __expf(z + z);
    return fmaf(-2.f, __builtin_amdgcn_rcpf(e + 1.f), 1.f);
}

// per-lane circuit constants for qubit q (scalars only — NO arrays, NO scratch)
template<int BF>
__device__ __forceinline__ void qubit_consts(const void* wry_, const void* wrz_, int q,
                                             float& ca_, float& da_, float& kr_, float& ki_) {
    float ry0, ry1, rz0, rz1;
    if constexpr (BF) {
        const __hip_bfloat16* WRY = (const __hip_bfloat16*)wry_;
        const __hip_bfloat16* WRZ = (const __hip_bfloat16*)wrz_;
        ry0 = __bfloat162float(WRY[q]);  ry1 = __bfloat162float(WRY[8 + q]);
        rz0 = __bfloat162float(WRZ[q]);  rz1 = __bfloat162float(WRZ[8 + q]);
    } else {
        const float* WRY = (const float*)wry_;
        const float* WRZ = (const float*)wrz_;
        ry0 = WRY[q];  ry1 = WRY[8 + q];
        rz0 = WRZ[q];  rz1 = WRZ[8 + q];
    }
    float cA = cosf(0.5f*ry0), sA = sinf(0.5f*ry0);
    float cB = cosf(0.5f*ry1), sB = sinf(0.5f*ry1);
    float p0c = cosf(0.5f*rz0), p0s = sinf(0.5f*rz0);
    float p1c = cosf(0.5f*rz1), p1s = sinf(0.5f*rz1);
    float g00r =  cA*p0c, g00i = -cA*p0s;
    float g01r = -sA*p0c, g01i =  sA*p0s;
    float g10r =  sA*p0c, g10i =  sA*p0s;
    float g11r =  cA*p0c, g11i =  cA*p0s;
    float h00r = cB*g00r - sB*g10r, h00i = cB*g00i - sB*g10i;
    float h01r = cB*g01r - sB*g11r, h01i = cB*g01i - sB*g11i;
    float h10r = sB*g00r + cB*g10r, h10i = sB*g00i + cB*g10i;
    float h11r = sB*g01r + cB*g11r, h11i = sB*g01i + cB*g11i;
    float f00r = h00r*p1c + h00i*p1s, f00i = h00i*p1c - h00r*p1s;
    float f01r = h01r*p1c + h01i*p1s, f01i = h01i*p1c - h01r*p1s;
    float f10r = h10r*p1c - h10i*p1s, f10i = h10i*p1c + h10r*p1s;
    float f11r = h11r*p1c - h11i*p1s, f11i = h11i*p1c + h11r*p1s;
    float DA = f00r*f00r + f00i*f00i - (f10r*f10r + f10i*f10i);
    float DB = f01r*f01r + f01i*f01i - (f11r*f11r + f11i*f11i);
    float Kr = (f00r*f01r + f00i*f01i) - (f10r*f11r + f10i*f11i);
    float Ki = (f00i*f01r - f00r*f01i) - (f10i*f11r - f10r*f11i);
    ca_ = 0.5f*(DA + DB); da_ = 0.5f*(DA - DB); kr_ = Kr; ki_ = Ki;
}

__global__ __launch_bounds__(TPB, 4) void fused_kernel(
    const void* H_, const void* WI_, const void* bin_, const void* WO_,
    const void* bout_, const void* wry_, const void* wrz_,
    const void* gam_, const void* bet_, void* out_)
{
    __shared__ uint sWin[8][DW];    // W_in rows verbatim: plane j, dword cp = cols (2cp,2cp+1)
    __shared__ uint sWout[8][DW];   // plane j, dword cp = (W_out[2cp][j], W_out[2cp+1][j])
    __shared__ uint sBout[DW], sGam[DW], sBet[DW];

    const int tid = threadIdx.x;
    const uint* Hd = (const uint*)H_;

    // ---- dtype sniff: block-uniform via syncthreads_count ----
    uint probe = Hd[(size_t)blockIdx.x * (SPB * DW) + tid];
    uint l0 = probe & 0xffffu, h0 = probe >> 16;
    uint e0 = (l0 >> 7) & 0xffu, e1 = (h0 >> 7) & 0xffu;
    bool okk = (l0 == 0u || (e0 >= 100u && e0 <= 133u)) &&
               (h0 == 0u || (e1 >= 100u && e1 <= 133u));
    int nok = __syncthreads_count(okk ? 1 : 0);

    if (nok >= TPB / 2) {
        // ================= bf16 fast path (identical to R4) =================
        const uint* WId = (const uint*)WI_;
        const uint* WOd = (const uint*)WO_;
        const uint* BOd = (const uint*)bout_;
        const uint* GAd = (const uint*)gam_;
        const uint* BEd = (const uint*)bet_;
        uint* Od = (uint*)out_;

        // ---- stage weights to LDS ----
        #pragma unroll
        for (int i = 0; i < 12; ++i)
            ((uint*)sWin)[tid + i*TPB] = WId[tid + i*TPB];
        for (int cp = tid; cp < DW; cp += TPB) {
            uint4 a = *(const uint4*)(WOd + (size_t)cp*8);      // row 2cp
            uint4 b = *(const uint4*)(WOd + (size_t)cp*8 + 4);  // row 2cp+1
            sWout[0][cp] = (a.x & 0xffffu) | (b.x << 16);
            sWout[1][cp] = (a.x >> 16)     | (b.x & 0xffff0000u);
            sWout[2][cp] = (a.y & 0xffffu) | (b.y << 16);
            sWout[3][cp] = (a.y >> 16)     | (b.y & 0xffff0000u);
            sWout[4][cp] = (a.z & 0xffffu) | (b.z << 16);
            sWout[5][cp] = (a.z >> 16)     | (b.z & 0xffff0000u);
            sWout[6][cp] = (a.w & 0xffffu) | (b.w << 16);
            sWout[7][cp] = (a.w >> 16)     | (b.w & 0xffff0000u);
            sBout[cp] = BOd[cp]; sGam[cp] = GAd[cp]; sBet[cp] = BEd[cp];
        }

        // ---- per-lane qubit constants (lane&7 owns its qubit) ----
        float ca_, da_, kr_, ki_;
        qubit_consts<1>(wry_, wrz_, tid & 7, ca_, da_, kr_, ki_);

        float bin0[8];
        {
            uint4 bi = *(const uint4*)bin_;
            bin0[0]=bflo(bi.x); bin0[1]=bfhi(bi.x); bin0[2]=bflo(bi.y); bin0[3]=bfhi(bi.y);
            bin0[4]=bflo(bi.z); bin0[5]=bfhi(bi.z); bin0[6]=bflo(bi.w); bin0[7]=bfhi(bi.w);
        }
        __syncthreads();

        const int lane = tid & 63;
        const int wv   = tid >> 6;
        const size_t r0 = (size_t)blockIdx.x * SPB + wv * 2;
        const uint* hA = Hd + r0 * DW;
        const uint* hB = hA + DW;

        // ---- phase A: z = hidden @ W_in^T (2 samples/wave) ----
        uint hAv[6], hBv[6];
        #pragma unroll
        for (int t = 0; t < 6; ++t) { hAv[t] = hA[t*64 + lane]; hBv[t] = hB[t*64 + lane]; }
        float zA[8] = {0,0,0,0,0,0,0,0}, zB[8] = {0,0,0,0,0,0,0,0};
        #pragma unroll
        for (int t = 0; t < 6; ++t) {
            int cp = t*64 + lane;
            float a0 = bflo(hAv[t]), a1 = bfhi(hAv[t]);
            float b0 = bflo(hBv[t]), b1 = bfhi(hBv[t]);
            #pragma unroll
            for (int j = 0; j < 8; ++j) {
                uint wj = sWin[j][cp];
                float w0 = bflo(wj), w1 = bfhi(wj);
                zA[j] = fmaf(a0, w0, zA[j]); zA[j] = fmaf(a1, w1, zA[j]);
                zB[j] = fmaf(b0, w0, zB[j]); zB[j] = fmaf(b1, w1, zB[j]);
            }
        }
        #pragma unroll
        for (int d = 1; d < 64; d <<= 1) {
            #pragma unroll
            for (int j = 0; j < 8; ++j) {
                zA[j] += __shfl_xor(zA[j], d, 64);
                zB[j] += __shfl_xor(zB[j], d, 64);
            }
        }

        // ---- circuit (both samples; wave-uniform result) ----
        float mA[8], mB[8];
        {
            float sc0[8], cc0[8], sc1[8], cc1[8];
            #pragma unroll
            for (int j = 0; j < 8; ++j) {
                float t0 = tanh_fast(zA[j] + bin0[j]);
                sc0[j] = __sinf(PI_F * t0); cc0[j] = __cosf(PI_F * t0);
                float t1 = tanh_fast(zB[j] + bin0[j]);
                sc1[j] = __sinf(PI_F * t1); cc1[j] = __cosf(PI_F * t1);
            }
            float PA0=1.f, PB0=1.f, F0r=1.f, F0i=0.f;
            float PA1=1.f, PB1=1.f, F1r=1.f, F1i=0.f;
            #pragma unroll
            for (int j = 1; j < 8; ++j) {
                float caj = __shfl(ca_, j, 64), daj = __shfl(da_, j, 64);
                float krj = __shfl(kr_, j, 64), kij = __shfl(ki_, j, 64);
                { float u = daj*cc0[j], v = fmaf(krj, sc0[j], caj);
                  mA[j] = fmaf(cc0[0], u, v);
                  PA0 *= (v+u); PB0 *= (v-u);
                  float fi = cc0[j]*kij;
                  float nr = F0r*krj - F0i*fi; F0i = F0r*fi + F0i*krj; F0r = nr; }
                { float u = daj*cc1[j], v = fmaf(krj, sc1[j], caj);
                  mB[j] = fmaf(cc1[0], u, v);
                  PA1 *= (v+u); PB1 *= (v-u);
                  float fi = cc1[j]*kij;
                  float nr = F1r*krj - F1i*fi; F1i = F1r*fi + F1i*krj; F1r = nr; }
            }
            float ca0 = __shfl(ca_, 0, 64), da0 = __shfl(da_, 0, 64);
            float kr0 = __shfl(kr_, 0, 64), ki0 = __shfl(ki_, 0, 64);
            float DA0 = ca0 + da0, DB0 = ca0 - da0;
            mA[0] = 0.5f*(1.f+cc0[0])*DA0*PA0 + 0.5f*(1.f-cc0[0])*DB0*PB0
                  + sc0[0]*(kr0*F0r - ki0*F0i);
            mB[0] = 0.5f*(1.f+cc1[0])*DA0*PA1 + 0.5f*(1.f-cc1[0])*DB0*PB1
                  + sc1[0]*(kr0*F1r - ki0*F1i);
        }

        // ---- phase C: y = meas @ W_out^T + b_out; LN; store ----
        float y0A[6], y1A[6], y0B[6], y1B[6];
        float s1A=0.f, s2A=0.f, s1B=0.f, s2B=0.f;
        #pragma unroll
        for (int t = 0; t < 6; ++t) {
            int cp = t*64 + lane;
            uint bo = sBout[cp];
            float v0A = bflo(bo), v1A = bfhi(bo);
            float v0B = v0A, v1B = v1A;
            #pragma unroll
            for (int j = 0; j < 8; ++j) {
                uint wj = sWout[j][cp];
                float w0 = bflo(wj), w1 = bfhi(wj);
                v0A = fmaf(mA[j], w0, v0A); v1A = fmaf(mA[j], w1, v1A);
                v0B = fmaf(mB[j], w0, v0B); v1B = fmaf(mB[j], w1, v1B);
            }
            y0A[t]=v0A; y1A[t]=v1A; y0B[t]=v0B; y1B[t]=v1B;
            s1A += v0A + v1A; s2A = fmaf(v0A,v0A,s2A); s2A = fmaf(v1A,v1A,s2A);
            s1B += v0B + v1B; s2B = fmaf(v0B,v0B,s2B); s2B = fmaf(v1B,v1B,s2B);
        }
        #pragma unroll
        for (int d = 1; d < 64; d <<= 1) {
            s1A += __shfl_xor(s1A, d, 64); s2A += __shfl_xor(s2A, d, 64);
            s1B += __shfl_xor(s1B, d, 64); s2B += __shfl_xor(s2B, d, 64);
        }
        float muA = s1A*(1.f/HID), rsA = rsqrtf(s2A*(1.f/HID) - muA*muA + 1e-5f);
        float muB = s1B*(1.f/HID), rsB = rsqrtf(s2B*(1.f/HID) - muB*muB + 1e-5f);
        uint* oA = Od + r0 * DW;
        uint* oB = oA + DW;
        #pragma unroll
        for (int t = 0; t < 6; ++t) {
            int cp = t*64 + lane;
            uint g = sGam[cp], be = sBet[cp];
            float g0 = bflo(g), g1 = bfhi(g), e0_ = bflo(be), e1_ = bfhi(be);
            float a0 = (y0A[t]-muA)*rsA*g0 + e0_;
            float a1 = (y1A[t]-muA)*rsA*g1 + e1_;
            oA[cp] = f2bf(a0) | (f2bf(a1) << 16);
            float b0 = (y0B[t]-muB)*rsB*g0 + e0_;
            float b1 = (y1B[t]-muB)*rsB*g1 + e1_;
            oB[cp] = f2bf(b0) | (f2bf(b1) << 16);
        }
    } else {
        // ===== fp32 fallback — scratch-free: scalars + shfl, no local arrays =====
        int s = blockIdx.x * TPB + tid;
        if (s >= BATCH) return;
        const int lane = tid & 63;
        const float* H  = (const float*)H_;
        const float* WI = (const float*)WI_;
        const float* WO = (const float*)WO_;
        const float* BI = (const float*)bin_;
        const float* BO = (const float*)bout_;
        const float* GA = (const float*)gam_;
        const float* BE = (const float*)bet_;
        float* O = (float*)out_;

        // lane&7 owns qubit constants; broadcast within each 8-lane group
        float ca_, da_, kr_, ki_;
        qubit_consts<0>(wry_, wrz_, lane & 7, ca_, da_, kr_, ki_);
        const int gb = lane & 56;                 // group base lane

        float z[8];
        #pragma unroll
        for (int j = 0; j < 8; ++j) z[j] = BI[j];
        for (int c = 0; c < HID; ++c) {
            float h = H[(size_t)s*HID + c];
            #pragma unroll
            for (int j = 0; j < 8; ++j) z[j] = fmaf(h, WI[j*HID + c], z[j]);
        }
        float sc[8], cc[8];
        #pragma unroll
        for (int j = 0; j < 8; ++j) {
            float t_ = tanhf(z[j]);
            sc[j] = sinpif(t_);
            cc[j] = cospif(t_);
        }
        float m[8];
        float PA = 1.f, PB = 1.f, Fr = 1.f, Fi = 0.f;
        #pragma unroll
        for (int j = 1; j < 8; ++j) {
            float caj = __shfl(ca_, gb | j, 64), daj = __shfl(da_, gb | j, 64);
            float krj = __shfl(kr_, gb | j, 64), kij = __shfl(ki_, gb | j, 64);
            float u = daj*cc[j];
            float v = fmaf(krj, sc[j], caj);
            m[j] = fmaf(cc[0], u, v);
            PA *= (v + u); PB *= (v - u);
            float fi = cc[j]*kij;
            float nr = Fr*krj - Fi*fi;
            Fi = Fr*fi + Fi*krj; Fr = nr;
        }
        {
            float ca0 = __shfl(ca_, gb, 64), da0 = __shfl(da_, gb, 64);
            float kr0 = __shfl(kr_, gb, 64), ki0 = __shfl(ki_, gb, 64);
            float DA0 = ca0 + da0, DB0 = ca0 - da0;
            m[0] = 0.5f*(1.f+cc[0])*DA0*PA + 0.5f*(1.f-cc[0])*DB0*PB
                 + sc[0]*(kr0*Fr - ki0*Fi);
        }
        float s1 = 0.f, s2 = 0.f;
        for (int h = 0; h < HID; ++h) {
            float v = BO[h];
            #pragma unroll
            for (int j = 0; j < 8; ++j) v = fmaf(m[j], WO[h*8 + j], v);
            s1 += v; s2 = fmaf(v, v, s2);
        }
        float mu = s1*(1.f/HID);
        float rs = rsqrtf(s2*(1.f/HID) - mu*mu + 1e-5f);
        for (int h = 0; h < HID; ++h) {
            float v = BO[h];
            #pragma unroll
            for (int j = 0; j < 8; ++j) v = fmaf(m[j], WO[h*8 + j], v);
            O[(size_t)s*HID + h] = (v - mu)*rs*GA[h] + BE[h];
        }
    }
}

extern "C" void kernel_launch(void* const* d_in, const int* in_sizes, int n_in,
                              void* d_out, int out_size, void* d_ws, size_t ws_size,
                              hipStream_t stream) {
    fused_kernel<<<NBLK, TPB, 0, stream>>>(
        d_in[0], d_in[1], d_in[2], d_in[3], d_in[4],
        d_in[5], d_in[6], d_in[7], d_in[8], d_out);
}